// Round 13
// baseline (255.806 us; speedup 1.0000x reference)
//
#include <hip/hip_runtime.h>
#include <cstddef>
#include <cstdint>

#define SQ    1023
#define HIDC  2048
#define NQC   10240
#define NKVC  1024

typedef unsigned short ushort_t;
typedef __bf16 bf16x8 __attribute__((ext_vector_type(8)));
typedef float  f32x4  __attribute__((ext_vector_type(4)));

__device__ __forceinline__ ushort_t f2bf(float x) {
  union { float f; uint32_t u; } v; v.f = x;
  uint32_t r = v.u + 0x7fffu + ((v.u >> 16) & 1u);   // RNE
  return (ushort_t)(r >> 16);
}

__device__ __forceinline__ ushort_t f2bf_fast(float x) {
  __bf16 b = (__bf16)x;
  return __builtin_bit_cast(ushort_t, b);
}

// raw v_exp_f32 (computes 2^x)
__device__ __forceinline__ float fexp2(float x) {
  float r;
  asm("v_exp_f32 %0, %1\n\ts_nop 0" : "=v"(r) : "v"(x));
  return r;
}

__device__ __forceinline__ void fexp2x4(float& a, float& b, float& c, float& d) {
  asm("v_exp_f32 %0, %0\n\t"
      "v_exp_f32 %1, %1\n\t"
      "v_exp_f32 %2, %2\n\t"
      "v_exp_f32 %3, %3\n\t"
      "s_nop 0"
      : "+v"(a), "+v"(b), "+v"(c), "+v"(d));
}

// ================= k_pre: tables U tconv(Wq,Wkv,Wo) U prep (one dispatch) ====
__device__ __forceinline__ void tconv_body(const float* __restrict__ in,
                                           ushort_t* __restrict__ out,
                                           int K, int N, int bx, int by,
                                           int tid, float (&t)[32][33]) {
  int n0 = bx * 32, k0 = by * 32;
  int r = tid >> 5, c = tid & 31;
  #pragma unroll
  for (int p = 0; p < 4; ++p)
    t[p * 8 + r][c] = in[(size_t)(k0 + p * 8 + r) * N + n0 + c];
  __syncthreads();
  #pragma unroll
  for (int p = 0; p < 4; ++p)
    out[(size_t)(n0 + p * 8 + r) * K + k0 + c] = f2bf(t[c][p * 8 + r]);
}

__global__ __launch_bounds__(256)
void k_pre(const float* __restrict__ Wq, const float* __restrict__ Wkv,
           const float* __restrict__ Wo, const float* __restrict__ hidden,
           const float* __restrict__ prevh,
           ushort_t* __restrict__ wqt, ushort_t* __restrict__ wkvt,
           ushort_t* __restrict__ wot, ushort_t* __restrict__ hbf,
           ushort_t* __restrict__ akv,
           float* __restrict__ cosT, float* __restrict__ sinT)
{
  __shared__ float tsh[32][33];
  const int tid = threadIdx.x;
  int b = blockIdx.x;
  if (b < 20480) { tconv_body(Wq, wqt, HIDC, NQC, b % 320, b / 320, tid, tsh); return; }
  b -= 20480;
  if (b < 4096)  { tconv_body(Wkv, wkvt, 4096, NKVC, b % 32, b / 32, tid, tsh); return; }
  b -= 4096;
  if (b < 4096)  { tconv_body(Wo, wot, HIDC, HIDC, b % 64, b / 64, tid, tsh); return; }
  b -= 4096;
  if (b < 2046) {
    int i = (b * 256 + tid) * 4;
    if (i >= SQ * 2048) return;
    int r = i >> 11, c = i & 2047;
    float4 h1 = *reinterpret_cast<const float4*>(hidden + (size_t)(r + 1) * 2048 + c);
    float4 h0 = *reinterpret_cast<const float4*>(hidden + (size_t)r * 2048 + c);
    float4 pv = *reinterpret_cast<const float4*>(prevh + (size_t)r * 2048 + c);
    uint2 a, bb, d;
    a.x  = (uint32_t)f2bf(h1.x) | ((uint32_t)f2bf(h1.y) << 16);
    a.y  = (uint32_t)f2bf(h1.z) | ((uint32_t)f2bf(h1.w) << 16);
    bb.x = (uint32_t)f2bf(pv.x) | ((uint32_t)f2bf(pv.y) << 16);
    bb.y = (uint32_t)f2bf(pv.z) | ((uint32_t)f2bf(pv.w) << 16);
    d.x  = (uint32_t)f2bf(h0.x) | ((uint32_t)f2bf(h0.y) << 16);
    d.y  = (uint32_t)f2bf(h0.z) | ((uint32_t)f2bf(h0.w) << 16);
    *reinterpret_cast<uint2*>(hbf + i) = a;
    *reinterpret_cast<uint2*>(akv + (size_t)r * 4096 + c) = bb;
    *reinterpret_cast<uint2*>(akv + (size_t)r * 4096 + 2048 + c) = d;
    return;
  }
  b -= 2046;
  {
    int idx = b * 256 + tid;
    if (idx >= SQ * 64) return;
    int t = idx >> 6, i = idx & 63;
    float inv = powf(10000.0f, -(float)i * (1.0f / 64.0f));
    float f = (float)t * inv;
    cosT[idx] = cosf(f);
    sinT[idx] = sinf(f);
  }
}

// ==== k_gemms: GEMM1 split-K x zq (f32 partials) U GEMM2 split-K x4 ==========
// GEMM1 blocks [0, 640*zq): plain 128x128 BK=32 3-buffer counted-vmcnt,
// kLen = 2048/zq, partial z -> qp0 (z=0) / qp1 (z=1). RoPE moved to attention.
__global__ __launch_bounds__(256)
void k_gemms(const ushort_t* __restrict__ hbf, const ushort_t* __restrict__ wqt,
             float* __restrict__ qp0, float* __restrict__ qp1, int zq,
             const ushort_t* __restrict__ akv, const ushort_t* __restrict__ wkvt,
             float* __restrict__ kvp)
{
  __shared__ __align__(16) ushort_t As[3][128 * 32];
  __shared__ __align__(16) ushort_t Bs[3][128 * 32];

  const int tid  = threadIdx.x;
  const int lane = tid & 63;
  const int w    = tid >> 6;
  const int wm   = w >> 1, wn = w & 1;
  const int fr   = lane & 15;
  const int kg   = (lane >> 4) * 8;
  const int g4   = lane >> 4;
  const int lrow = lane >> 2;
  const int lk   = (lane & 3) * 8;
  const int nG1  = 640 * zq;

  if ((int)blockIdx.x < nG1) {
    // ---------------- GEMM1 split-K (m97 3-buffer counted-vmcnt) ------------
    const int Kd = 2048;
    const int z  = (int)blockIdx.x >= 640 ? 1 : 0;
    const int b  = blockIdx.x - z * 640;
    const int kLen = Kd / zq;
    const int m0 = (b / 80) * 128, n0 = (b % 80) * 128;
    const int kOff = z * kLen;
    float* C = z ? qp1 : qp0;
    const ushort_t* A  = hbf;
    const ushort_t* Bt = wqt;

    f32x4 acc[4][4];
    #pragma unroll
    for (int i = 0; i < 4; ++i)
      #pragma unroll
      for (int j = 0; j < 4; ++j) acc[i][j] = (f32x4){0.f, 0.f, 0.f, 0.f};

    auto STAGE = [&](int bb, int k0) {
      #pragma unroll
      for (int c = 0; c < 2; ++c) {
        int ch  = w + c * 4;
        int row = ch * 16 + lrow;
        const ushort_t* ga = A  + (size_t)(m0 + row) * Kd + k0 + lk;
        const ushort_t* gb = Bt + (size_t)(n0 + row) * Kd + k0 + lk;
        __builtin_amdgcn_global_load_lds(
            (const __attribute__((address_space(1))) void*)ga,
            (__attribute__((address_space(3))) void*)(&As[bb][0] + ch * 512), 16, 0, 0);
        __builtin_amdgcn_global_load_lds(
            (const __attribute__((address_space(1))) void*)gb,
            (__attribute__((address_space(3))) void*)(&Bs[bb][0] + ch * 512), 16, 0, 0);
      }
    };

    const int nt = kLen / 32;
    STAGE(0, kOff);
    STAGE(1, kOff + 32);

    int cur = 0;
    for (int t = 0; t < nt; ++t) {
      if (t + 1 < nt) {
        asm volatile("s_waitcnt vmcnt(4)" ::: "memory");
      } else {
        asm volatile("s_waitcnt vmcnt(0)" ::: "memory");
      }
      __builtin_amdgcn_s_barrier();
      if (t + 2 < nt) {
        int sb = cur + 2; if (sb >= 3) sb -= 3;
        STAGE(sb, kOff + (t + 2) * 32);
      }

      bf16x8 av[4], bv[4];
      #pragma unroll
      for (int mi = 0; mi < 4; ++mi)
        av[mi] = *reinterpret_cast<const bf16x8*>(&As[cur][0] + (wm * 64 + mi * 16 + fr) * 32 + kg);
      #pragma unroll
      for (int nj = 0; nj < 4; ++nj)
        bv[nj] = *reinterpret_cast<const bf16x8*>(&Bs[cur][0] + (wn * 64 + nj * 16 + fr) * 32 + kg);
      #pragma unroll
      for (int mi = 0; mi < 4; ++mi)
        #pragma unroll
        for (int nj = 0; nj < 4; ++nj)
          acc[mi][nj] = __builtin_amdgcn_mfma_f32_16x16x32_bf16(av[mi], bv[nj], acc[mi][nj], 0, 0, 0);

      cur = (cur == 2) ? 0 : cur + 1;
    }

    #pragma unroll
    for (int mi = 0; mi < 4; ++mi) {
      #pragma unroll
      for (int nj = 0; nj < 4; ++nj) {
        int rbase = m0 + wm * 64 + mi * 16 + g4 * 4;
        int col   = n0 + wn * 64 + nj * 16 + fr;
        #pragma unroll
        for (int r = 0; r < 4; ++r) {
          int gr = rbase + r;
          if (gr < SQ) C[(size_t)gr * 10240 + col] = acc[mi][nj][r];
        }
      }
    }
  } else {
    // ---------------- GEMM2 64x128 split-K x4 ----
    const int u = blockIdx.x - nG1;
    const int Kd = 4096, M = SQ, N = NKVC, kLen = 1024;
    const int n0 = (u & 7) * 128, m0 = ((u >> 3) & 15) * 64;
    const int kOff = (u >> 7) * kLen;
    float* C = kvp + (size_t)(u >> 7) * M * N;
    ushort_t* As64 = &As[0][0];
    ushort_t* Bs64 = &Bs[0][0];

    const int arow = tid >> 2, aslot = (tid & 3) * 8;
    const int l15 = lane & 15;

    f32x4 acc[2][4];
    #pragma unroll
    for (int i = 0; i < 2; ++i)
      #pragma unroll
      for (int j = 0; j < 4; ++j) acc[i][j] = (f32x4){0.f, 0.f, 0.f, 0.f};

    for (int k0 = kOff; k0 < kOff + kLen; k0 += 32) {
      {
        const ushort_t* ga = akv + (size_t)(m0 + arow) * Kd + k0 + aslot;
        __builtin_amdgcn_global_load_lds(
            (const __attribute__((address_space(1))) void*)ga,
            (__attribute__((address_space(3))) void*)(As64 + w * 512), 16, 0, 0);
      }
      #pragma unroll
      for (int c = 0; c < 2; ++c) {
        int uu = c * 256 + tid;
        const ushort_t* gb = wkvt + (size_t)(n0 + (uu >> 2)) * Kd + k0 + (uu & 3) * 8;
        __builtin_amdgcn_global_load_lds(
            (const __attribute__((address_space(1))) void*)gb,
            (__attribute__((address_space(3))) void*)(Bs64 + (c * 256 + w * 64) * 8), 16, 0, 0);
      }
      __syncthreads();

      bf16x8 av[2], bv[4];
      #pragma unroll
      for (int mi = 0; mi < 2; ++mi)
        av[mi] = *reinterpret_cast<const bf16x8*>(As64 + (wm * 32 + mi * 16 + fr) * 32 + kg);
      #pragma unroll
      for (int nj = 0; nj < 4; ++nj)
        bv[nj] = *reinterpret_cast<const bf16x8*>(Bs64 + (wn * 64 + nj * 16 + fr) * 32 + kg);
      #pragma unroll
      for (int mi = 0; mi < 2; ++mi)
        #pragma unroll
        for (int nj = 0; nj < 4; ++nj)
          acc[mi][nj] = __builtin_amdgcn_mfma_f32_16x16x32_bf16(av[mi], bv[nj], acc[mi][nj], 0, 0, 0);
      __syncthreads();
    }

    #pragma unroll
    for (int mi = 0; mi < 2; ++mi) {
      #pragma unroll
      for (int nj = 0; nj < 4; ++nj) {
        int rbase = m0 + wm * 32 + mi * 16 + g4 * 4;
        int col   = n0 + wn * 64 + nj * 16 + l15;
        #pragma unroll
        for (int r = 0; r < 4; ++r) {
          int gr = rbase + r;
          if (gr < M) C[(size_t)gr * N + col] = acc[mi][nj][r];
        }
      }
    }
  }
}

// ============ k_kv: rope_k (blocks 0-1022) U vtrans (blocks 1023-1534) =======
__global__ __launch_bounds__(256)
void k_kv(const float* __restrict__ kvp, ushort_t* __restrict__ kb,
          ushort_t* __restrict__ vt, const float* __restrict__ cosT,
          const float* __restrict__ sinT)
{
  __shared__ float tile[32][33];
  const int tid = threadIdx.x;
  int b = blockIdx.x;
  if (b < 1023) {
    int idx = b * 256 + tid;
    if (idx >= SQ * 4 * 64) return;
    int d   = idx & 63;
    int kvh = (idx >> 6) & 3;
    int t   = idx >> 8;
    size_t src = (size_t)t * 1024 + kvh * 128 + d;
    float x0 = 0.f, x1 = 0.f;
    #pragma unroll
    for (int z = 0; z < 4; ++z) {
      x0 += kvp[(size_t)z * (SQ * 1024) + src];
      x1 += kvp[(size_t)z * (SQ * 1024) + src + 64];
    }
    float c = cosT[t * 64 + d], s = sinT[t * 64 + d];
    size_t dst = (size_t)t * 512 + kvh * 128 + d;
    kb[dst]      = f2bf(x0 * c - x1 * s);
    kb[dst + 64] = f2bf(x1 * c + x0 * s);
    return;
  }
  b -= 1023;
  {
    int v0 = (b & 15) * 32;
    int t0 = (b >> 4) * 32;
    int r = tid >> 5, c = tid & 31;
    #pragma unroll
    for (int p = 0; p < 4; ++p) {
      int t = t0 + p * 8 + r;
      float s = 0.f;
      if (t < SQ) {
        size_t src = (size_t)t * 1024 + 512 + v0 + c;
        #pragma unroll
        for (int z = 0; z < 4; ++z) s += kvp[(size_t)z * (SQ * 1024) + src];
      }
      tile[p * 8 + r][c] = s;
    }
    __syncthreads();
    #pragma unroll
    for (int p = 0; p < 4; ++p) {
      int v = v0 + p * 8 + r;
      vt[(size_t)v * 1024 + t0 + c] = f2bf(tile[c][p * 8 + r]);
    }
  }
}

// == bf16 MFMA GEMM, 128x128 tile, BK=32, 3-buffer + counted vmcnt (GEMM3) ====
__global__ __launch_bounds__(256)
void k_gemm3buf(const ushort_t* __restrict__ A, const ushort_t* __restrict__ Bt,
                float* __restrict__ C, int M, int N, int Kd)
{
  __shared__ __align__(16) ushort_t As[3][128 * 32];
  __shared__ __align__(16) ushort_t Bs[3][128 * 32];

  const int tid  = threadIdx.x;
  const int lane = tid & 63;
  const int w    = tid >> 6;
  const int wm   = w >> 1, wn = w & 1;
  const int fr   = lane & 15;
  const int kg   = (lane >> 4) * 8;
  const int m0   = blockIdx.y * 128, n0 = blockIdx.x * 128;

  const int lrow = lane >> 2;
  const int lk   = (lane & 3) * 8;

  f32x4 acc[4][4];
  #pragma unroll
  for (int i = 0; i < 4; ++i)
    #pragma unroll
    for (int j = 0; j < 4; ++j) acc[i][j] = (f32x4){0.f, 0.f, 0.f, 0.f};

  auto STAGE = [&](int b, int k0) {
    #pragma unroll
    for (int c = 0; c < 2; ++c) {
      int ch  = w + c * 4;
      int row = ch * 16 + lrow;
      const ushort_t* ga = A  + (size_t)(m0 + row) * Kd + k0 + lk;
      const ushort_t* gb = Bt + (size_t)(n0 + row) * Kd + k0 + lk;
      __builtin_amdgcn_global_load_lds(
          (const __attribute__((address_space(1))) void*)ga,
          (__attribute__((address_space(3))) void*)(&As[b][0] + ch * 512), 16, 0, 0);
      __builtin_amdgcn_global_load_lds(
          (const __attribute__((address_space(1))) void*)gb,
          (__attribute__((address_space(3))) void*)(&Bs[b][0] + ch * 512), 16, 0, 0);
    }
  };

  const int nt = Kd / 32;
  STAGE(0, 0);
  STAGE(1, 32);

  int cur = 0;
  for (int t = 0; t < nt; ++t) {
    if (t + 1 < nt) {
      asm volatile("s_waitcnt vmcnt(4)" ::: "memory");
    } else {
      asm volatile("s_waitcnt vmcnt(0)" ::: "memory");
    }
    __builtin_amdgcn_s_barrier();
    if (t + 2 < nt) {
      int sb = cur + 2; if (sb >= 3) sb -= 3;
      STAGE(sb, (t + 2) * 32);
    }

    bf16x8 av[4], bv[4];
    #pragma unroll
    for (int mi = 0; mi < 4; ++mi)
      av[mi] = *reinterpret_cast<const bf16x8*>(&As[cur][0] + (wm * 64 + mi * 16 + fr) * 32 + kg);
    #pragma unroll
    for (int nj = 0; nj < 4; ++nj)
      bv[nj] = *reinterpret_cast<const bf16x8*>(&Bs[cur][0] + (wn * 64 + nj * 16 + fr) * 32 + kg);
    #pragma unroll
    for (int mi = 0; mi < 4; ++mi)
      #pragma unroll
      for (int nj = 0; nj < 4; ++nj)
        acc[mi][nj] = __builtin_amdgcn_mfma_f32_16x16x32_bf16(av[mi], bv[nj], acc[mi][nj], 0, 0, 0);

    cur = (cur == 2) ? 0 : cur + 1;
  }

  #pragma unroll
  for (int mi = 0; mi < 4; ++mi) {
    #pragma unroll
    for (int nj = 0; nj < 4; ++nj) {
      int rbase = m0 + wm * 64 + mi * 16 + (lane >> 4) * 4;
      int col   = n0 + wn * 64 + nj * 16 + fr;
      #pragma unroll
      for (int r = 0; r < 4; ++r) {
        int gr = rbase + r;
        if (gr < M) C[(size_t)gr * N + col] = acc[mi][nj][r];
      }
    }
  }
}

// ======================= MFMA flash attention (swapped-QK, exp2 domain) ======
// Q-setup fuses the GEMM1 split-K reduce + RoPE + scale (RoPE is linear, so
// it commutes with the partial sum; lane holds both halves d and d+64).
__global__ __launch_bounds__(256)
void k_attn_mfma(const float* __restrict__ qp0, const float* __restrict__ qp1,
                 int zq, const ushort_t* __restrict__ kb,
                 const ushort_t* __restrict__ vt, ushort_t* __restrict__ oattb,
                 const float* __restrict__ cosT, const float* __restrict__ sinT)
{
  __shared__ __align__(16) ushort_t Ks[64 * 128];
  __shared__ __align__(16) ushort_t Vs[128 * 64];
  __shared__ __align__(16) ushort_t Ps[4][16 * 64]; // per-wave P [16 q][64 kv], XOR-swz

  const int tid  = threadIdx.x;
  const int lane = tid & 63;
  const int w    = tid >> 6;
  const int l15  = lane & 15;
  const int g4   = lane >> 4;
  const int gh   = blockIdx.x;
  const int g = gh >> 4, h = gh & 15, kvh = (gh & 15) >> 2;
  const int qt = 15 - blockIdx.y;
  const int t0 = qt * 64;
  const int tq = t0 + w * 16 + l15;        // this lane's q row

  // ---- Q setup: sum partials, RoPE, scale, pack to bf16 A-frags ----
  bf16x8 av[4];
  {
    const int tqc = (tq < SQ) ? tq : (SQ - 1);   // clamp (dead lanes only)
    const size_t qoff = ((size_t)(g * SQ + tqc)) * 2048 + h * 128 + g4 * 8;
    float x[4][8];
    #pragma unroll
    for (int kk = 0; kk < 4; ++kk) {
      f32x4 a0 = *reinterpret_cast<const f32x4*>(qp0 + qoff + kk * 32);
      f32x4 a1 = *reinterpret_cast<const f32x4*>(qp0 + qoff + kk * 32 + 4);
      if (zq > 1) {
        a0 += *reinterpret_cast<const f32x4*>(qp1 + qoff + kk * 32);
        a1 += *reinterpret_cast<const f32x4*>(qp1 + qoff + kk * 32 + 4);
      }
      #pragma unroll
      for (int j = 0; j < 4; ++j) { x[kk][j] = a0[j]; x[kk][j + 4] = a1[j]; }
    }
    const float scq = 0.1275174485f;   // log2(e) / sqrt(128)
    const float* ct = cosT + tqc * 64 + g4 * 8;
    const float* st = sinT + tqc * 64 + g4 * 8;
    #pragma unroll
    for (int kk = 0; kk < 2; ++kk) {
      #pragma unroll
      for (int j = 0; j < 8; ++j) {
        float c = ct[kk * 32 + j], s = st[kk * 32 + j];
        float x0 = x[kk][j], x1 = x[kk + 2][j];
        av[kk][j]     = (__bf16)((x0 * c - x1 * s) * scq);
        av[kk + 2][j] = (__bf16)((x1 * c + x0 * s) * scq);
      }
    }
  }

  f32x4 acc[8];
  #pragma unroll
  for (int dt = 0; dt < 8; ++dt) acc[dt] = (f32x4){0.f, 0.f, 0.f, 0.f};
  float lsum = 0.f;
  float m = -1e30f;

  char* pwb = (char*)&Ps[w][0] + l15 * 128;   // this lane's P row (bytes)
  const int pswz = (l15 & 7) << 4;            // byte XOR within row

  for (int jt = 0; jt <= qt; ++jt) {
    int u0 = jt * 64;
    #pragma unroll
    for (int i = 0; i < 4; ++i) {
      int c = (w * 4 + i) * 64 + lane;
      int kv = c >> 4, sl = c & 15;
      const ushort_t* srck = kb + (size_t)(u0 + kv) * 512 + kvh * 128 + ((sl ^ (kv & 7)) << 3);
      __builtin_amdgcn_global_load_lds(
          (const __attribute__((address_space(1))) void*)srck,
          (__attribute__((address_space(3))) void*)(Ks + (w * 4 + i) * 512), 16, 0, 0);
      int d = c >> 3, sv = c & 7;
      const ushort_t* srcv = vt + (size_t)(kvh * 128 + d) * 1024 + u0 + ((sv ^ (d & 7)) << 3);
      __builtin_amdgcn_global_load_lds(
          (const __attribute__((address_space(1))) void*)srcv,
          (__attribute__((address_space(3))) void*)(Vs + (w * 4 + i) * 512), 16, 0, 0);
    }
    __syncthreads();

    // S^T = K Q^T  (S[ct][r]: row kv = ct*16 + g4*4 + r, col q = l15)
    f32x4 S[4];
    #pragma unroll
    for (int ct = 0; ct < 4; ++ct) S[ct] = (f32x4){0.f, 0.f, 0.f, 0.f};
    #pragma unroll
    for (int ct = 0; ct < 4; ++ct) {
      int kv = ct * 16 + l15;
      #pragma unroll
      for (int kk = 0; kk < 4; ++kk) {
        bf16x8 kvf = *reinterpret_cast<const bf16x8*>(
            Ks + kv * 128 + ((((kk << 2) | g4) ^ (kv & 7)) << 3));
        S[ct] = __builtin_amdgcn_mfma_f32_16x16x32_bf16(kvf, av[kk], S[ct], 0, 0, 0);
      }
    }
    // causal mask: u = u0 + ct*16 + g4*4 + r vs t = tq
    if (jt == qt) {
      #pragma unroll
      for (int ct = 0; ct < 4; ++ct) {
        int ub = u0 + ct * 16 + g4 * 4;
        #pragma unroll
        for (int r = 0; r < 4; ++r)
          if (ub + r > tq) S[ct][r] = -1e30f;
      }
    }
    // in-lane max tree + 2 shfl
    float a0 = fmaxf(fmaxf(S[0][0], S[0][1]), fmaxf(S[0][2], S[0][3]));
    float a1 = fmaxf(fmaxf(S[1][0], S[1][1]), fmaxf(S[1][2], S[1][3]));
    float a2 = fmaxf(fmaxf(S[2][0], S[2][1]), fmaxf(S[2][2], S[2][3]));
    float a3 = fmaxf(fmaxf(S[3][0], S[3][1]), fmaxf(S[3][2], S[3][3]));
    float tm = fmaxf(fmaxf(a0, a1), fmaxf(a2, a3));
    tm = fmaxf(tm, __shfl_xor(tm, 16));
    tm = fmaxf(tm, __shfl_xor(tm, 32));

    // defer-max (T13, log2 units: P bounded by 2^8)
    bool need = tm > m + 8.f;
    if (__any(need)) {
      float mn = fmaxf(m, tm);
      float corr = fexp2(m - mn);
      m = mn;
      lsum *= corr;
      #pragma unroll
      for (int dt = 0; dt < 8; ++dt) acc[dt] *= corr;
    }

    // exp + pack + b64 store + partial sum, per ct
    float ps = 0.f;
    #pragma unroll
    for (int ct = 0; ct < 4; ++ct) {
      float e0 = S[ct][0] - m;
      float e1 = S[ct][1] - m;
      float e2 = S[ct][2] - m;
      float e3 = S[ct][3] - m;
      fexp2x4(e0, e1, e2, e3);
      ps += (e0 + e1) + (e2 + e3);
      uint2 pv;
      pv.x = (uint32_t)f2bf_fast(e0) | ((uint32_t)f2bf_fast(e1) << 16);
      pv.y = (uint32_t)f2bf_fast(e2) | ((uint32_t)f2bf_fast(e3) << 16);
      *reinterpret_cast<uint2*>(pwb + ((ct * 32 + g4 * 8) ^ pswz)) = pv;
    }
    ps += __shfl_xor(ps, 16);
    ps += __shfl_xor(ps, 32);
    lsum += ps;

    // O^T += V^T P^T : acc[dt] rows d = dt*16 + g4*4 + r, col q = l15
    #pragma unroll
    for (int kk = 0; kk < 2; ++kk) {
      bf16x8 pa = *reinterpret_cast<const bf16x8*>(pwb + ((kk * 64 + g4 * 16) ^ pswz));
      #pragma unroll
      for (int dt = 0; dt < 8; ++dt) {
        int d = dt * 16 + l15;
        bf16x8 vv = *reinterpret_cast<const bf16x8*>(
            Vs + d * 64 + ((((kk << 2) | g4) ^ (d & 7)) << 3));
        acc[dt] = __builtin_amdgcn_mfma_f32_16x16x32_bf16(vv, pa, acc[dt], 0, 0, 0);
      }
    }
    __syncthreads();
  }

  // epilogue: lane writes O[tq][d = dt*16 + g4*4 + 0..3] as packed 8B
  if (tq < SQ) {
    float inv = 1.f / lsum;
    ushort_t* dst = oattb + ((size_t)(g * SQ + tq)) * 2048 + h * 128;
    #pragma unroll
    for (int dt = 0; dt < 8; ++dt) {
      uint2 ov;
      ov.x = (uint32_t)f2bf_fast(acc[dt][0] * inv) | ((uint32_t)f2bf_fast(acc[dt][1] * inv) << 16);
      ov.y = (uint32_t)f2bf_fast(acc[dt][2] * inv) | ((uint32_t)f2bf_fast(acc[dt][3] * inv) << 16);
      *reinterpret_cast<uint2*>(dst + dt * 16 + g4 * 4) = ov;
    }
  }
}

// ======================= launch =======================
extern "C" void kernel_launch(void* const* d_in, const int* in_sizes, int n_in,
                              void* d_out, int out_size, void* d_ws, size_t ws_size,
                              hipStream_t stream) {
  const float* hidden = (const float*)d_in[0];   // (1024, 2048)
  const float* prevh  = (const float*)d_in[1];   // (1023, 2048)
  const float* Wq     = (const float*)d_in[4];   // (2048, 10240)
  const float* Wkv    = (const float*)d_in[5];   // (4096, 1024)
  const float* Wo     = (const float*)d_in[6];   // (2048, 2048)
  float* out = (float*)d_out;                    // (5115, 2048)

  char* ws  = (char*)d_ws;
  char* ws0 = ws;
  float*    kvp   = (float*)ws;                        ws += (size_t)4 * SQ * 1024 * 4;
  float*    cosT  = (float*)ws;                        ws += (size_t)65472 * 4;
  float*    sinT  = (float*)ws;                        ws += (size_t)65472 * 4;
  ushort_t* kb    = (ushort_t*)ws;                     ws += (size_t)1024 * 512 * 2;
  ushort_t* vtb   = (ushort_t*)ws;                     ws += (size_t)512 * 1024 * 2;
  ushort_t* hbf   = (ushort_t*)ws;                     ws += (size_t)1024 * 2048 * 2;
  ushort_t* akv   = (ushort_t*)ws;                     ws += (size_t)1024 * 4096 * 2;
  ushort_t* oattb = (ushort_t*)ws;                     ws += (size_t)5120 * 2048 * 2;
  ushort_t* wqt   = (ushort_t*)ws;                     ws += (size_t)10240 * 2048 * 2;
  ushort_t* wkvt  = (ushort_t*)ws;                     ws += (size_t)1024 * 4096 * 2;
  ushort_t* wot   = (ushort_t*)ws;                     ws += (size_t)2048 * 2048 * 2;
  float*    qp1   = (float*)ws;                        ws += (size_t)5120 * 2048 * 4;  // split-K partial 1 (last!)

  // split-K x2 for GEMM1 only if ws has room for partial 1
  const int zq = (ws_size >= (size_t)(ws - ws0)) ? 2 : 1;

  float* qp0 = out;   // f32 q_proj partial 0 lives in d_out (1023*10240, exact fit)

  // 1. all preprocessing in one dispatch (tconv x3 + prep + tables)
  k_pre<<<dim3(20480 + 4096 + 4096 + 2046 + 256), dim3(256), 0, stream>>>(
      Wq, Wkv, Wo, hidden, prevh, wqt, wkvt, wot, hbf, akv, cosT, sinT);

  // 2. GEMM1 split-K x zq and GEMM2 co-scheduled (640*zq + 512 blocks)
  k_gemms<<<dim3(640 * zq + 512), dim3(256), 0, stream>>>(
      hbf, wqt, qp0, qp1, zq, akv, wkvt, kvp);

  // 3. K rope + V transpose (fold 4 kv partials), one dispatch
  k_kv<<<dim3(1023 + 512), dim3(256), 0, stream>>>(kvp, kb, vtb, cosT, sinT);

  // 4. MFMA flash attention (swapped-QK; fused Q reduce+RoPE) -> bf16 O
  k_attn_mfma<<<dim3(80, 16), dim3(256), 0, stream>>>(
      qp0, qp1, zq, kb, vtb, oattb, cosT, sinT);

  // 5. out = O_att @ Wo
  k_gemm3buf<<<dim3(HIDC / 128, 40), dim3(256), 0, stream>>>(oattb, wot, out, 5115, HIDC, 2048);
}

// Round 14
// 244.921 us; speedup vs baseline: 1.0444x; 1.0444x over previous
//
#include <hip/hip_runtime.h>
#include <cstddef>
#include <cstdint>

#define SQ    1023
#define HIDC  2048
#define NQC   10240
#define NKVC  1024

typedef unsigned short ushort_t;
typedef __bf16 bf16x8 __attribute__((ext_vector_type(8)));
typedef float  f32x4  __attribute__((ext_vector_type(4)));

__device__ __forceinline__ ushort_t f2bf(float x) {
  union { float f; uint32_t u; } v; v.f = x;
  uint32_t r = v.u + 0x7fffu + ((v.u >> 16) & 1u);   // RNE
  return (ushort_t)(r >> 16);
}

__device__ __forceinline__ ushort_t f2bf_fast(float x) {
  __bf16 b = (__bf16)x;
  return __builtin_bit_cast(ushort_t, b);
}

// raw v_exp_f32 (computes 2^x)
__device__ __forceinline__ float fexp2(float x) {
  float r;
  asm("v_exp_f32 %0, %1\n\ts_nop 0" : "=v"(r) : "v"(x));
  return r;
}

__device__ __forceinline__ void fexp2x4(float& a, float& b, float& c, float& d) {
  asm("v_exp_f32 %0, %0\n\t"
      "v_exp_f32 %1, %1\n\t"
      "v_exp_f32 %2, %2\n\t"
      "v_exp_f32 %3, %3\n\t"
      "s_nop 0"
      : "+v"(a), "+v"(b), "+v"(c), "+v"(d));
}

// ======================= shared tconv body =======================
__device__ __forceinline__ void tconv_body(const float* __restrict__ in,
                                           ushort_t* __restrict__ out,
                                           int K, int N, int bx, int by,
                                           int tid, float (&t)[32][33]) {
  int n0 = bx * 32, k0 = by * 32;
  int r = tid >> 5, c = tid & 31;
  #pragma unroll
  for (int p = 0; p < 4; ++p)
    t[p * 8 + r][c] = in[(size_t)(k0 + p * 8 + r) * N + n0 + c];
  __syncthreads();
  #pragma unroll
  for (int p = 0; p < 4; ++p)
    out[(size_t)(n0 + p * 8 + r) * K + k0 + c] = f2bf(t[c][p * 8 + r]);
}

// ================= k_pre: tables U tconv(Wq,Wkv) U prep (one dispatch) =======
// block roles: [0,20480) tconv Wq | [20480,24576) tconv Wkv |
// [24576,26622) prep | [26622,26878) rope tables.  (Wo tconv moved to k_gemms)
__global__ __launch_bounds__(256)
void k_pre(const float* __restrict__ Wq, const float* __restrict__ Wkv,
           const float* __restrict__ hidden, const float* __restrict__ prevh,
           ushort_t* __restrict__ wqt, ushort_t* __restrict__ wkvt,
           ushort_t* __restrict__ hbf, ushort_t* __restrict__ akv,
           float* __restrict__ cosT, float* __restrict__ sinT)
{
  __shared__ float tsh[32][33];
  const int tid = threadIdx.x;
  int b = blockIdx.x;
  if (b < 20480) { tconv_body(Wq, wqt, HIDC, NQC, b % 320, b / 320, tid, tsh); return; }
  b -= 20480;
  if (b < 4096)  { tconv_body(Wkv, wkvt, 4096, NKVC, b % 32, b / 32, tid, tsh); return; }
  b -= 4096;
  if (b < 2046) {
    int i = (b * 256 + tid) * 4;
    if (i >= SQ * 2048) return;
    int r = i >> 11, c = i & 2047;
    float4 h1 = *reinterpret_cast<const float4*>(hidden + (size_t)(r + 1) * 2048 + c);
    float4 h0 = *reinterpret_cast<const float4*>(hidden + (size_t)r * 2048 + c);
    float4 pv = *reinterpret_cast<const float4*>(prevh + (size_t)r * 2048 + c);
    uint2 a, bb, d;
    a.x  = (uint32_t)f2bf(h1.x) | ((uint32_t)f2bf(h1.y) << 16);
    a.y  = (uint32_t)f2bf(h1.z) | ((uint32_t)f2bf(h1.w) << 16);
    bb.x = (uint32_t)f2bf(pv.x) | ((uint32_t)f2bf(pv.y) << 16);
    bb.y = (uint32_t)f2bf(pv.z) | ((uint32_t)f2bf(pv.w) << 16);
    d.x  = (uint32_t)f2bf(h0.x) | ((uint32_t)f2bf(h0.y) << 16);
    d.y  = (uint32_t)f2bf(h0.z) | ((uint32_t)f2bf(h0.w) << 16);
    *reinterpret_cast<uint2*>(hbf + i) = a;
    *reinterpret_cast<uint2*>(akv + (size_t)r * 4096 + c) = bb;
    *reinterpret_cast<uint2*>(akv + (size_t)r * 4096 + 2048 + c) = d;
    return;
  }
  b -= 2046;
  {
    int idx = b * 256 + tid;
    if (idx >= SQ * 64) return;
    int t = idx >> 6, i = idx & 63;
    float inv = powf(10000.0f, -(float)i * (1.0f / 64.0f));
    float f = (float)t * inv;
    cosT[idx] = cosf(f);
    sinT[idx] = sinf(f);
  }
}

// == k_gemms: GEMM1+RoPE (0-639) U GEMM2 split-Kx2 (640-895) U tconv Wo (896-4991)
__global__ __launch_bounds__(256)
void k_gemms(const ushort_t* __restrict__ hbf, const ushort_t* __restrict__ wqt,
             ushort_t* __restrict__ qbb, const float* __restrict__ cosT,
             const float* __restrict__ sinT,
             const ushort_t* __restrict__ akv, const ushort_t* __restrict__ wkvt,
             float* __restrict__ kvp,
             const float* __restrict__ Wo, ushort_t* __restrict__ wot)
{
  __shared__ __align__(16) ushort_t As[3][128 * 32];
  __shared__ __align__(16) ushort_t Bs[3][128 * 32];

  const int tid  = threadIdx.x;
  const int lane = tid & 63;
  const int w    = tid >> 6;
  const int wm   = w >> 1, wn = w & 1;
  const int fr   = lane & 15;
  const int kg   = (lane >> 4) * 8;
  const int g4   = lane >> 4;
  const int lrow = lane >> 2;
  const int lk   = (lane & 3) * 8;

  if (blockIdx.x < 640) {
    // ---------------- GEMM1 + fused RoPE (m97 3-buffer counted-vmcnt) -------
    const int Kd = 2048;
    const int m0 = (blockIdx.x / 80) * 128, n0 = (blockIdx.x % 80) * 128;
    const ushort_t* A  = hbf;
    const ushort_t* Bt = wqt;

    f32x4 acc[4][4];
    #pragma unroll
    for (int i = 0; i < 4; ++i)
      #pragma unroll
      for (int j = 0; j < 4; ++j) acc[i][j] = (f32x4){0.f, 0.f, 0.f, 0.f};

    auto STAGE = [&](int b, int k0) {
      #pragma unroll
      for (int c = 0; c < 2; ++c) {
        int ch  = w + c * 4;
        int row = ch * 16 + lrow;
        const ushort_t* ga = A  + (size_t)(m0 + row) * Kd + k0 + lk;
        const ushort_t* gb = Bt + (size_t)(n0 + row) * Kd + k0 + lk;
        __builtin_amdgcn_global_load_lds(
            (const __attribute__((address_space(1))) void*)ga,
            (__attribute__((address_space(3))) void*)(&As[b][0] + ch * 512), 16, 0, 0);
        __builtin_amdgcn_global_load_lds(
            (const __attribute__((address_space(1))) void*)gb,
            (__attribute__((address_space(3))) void*)(&Bs[b][0] + ch * 512), 16, 0, 0);
      }
    };

    const int nt = Kd / 32;
    STAGE(0, 0);
    STAGE(1, 32);

    int cur = 0;
    for (int t = 0; t < nt; ++t) {
      if (t + 1 < nt) {
        asm volatile("s_waitcnt vmcnt(4)" ::: "memory");
      } else {
        asm volatile("s_waitcnt vmcnt(0)" ::: "memory");
      }
      __builtin_amdgcn_s_barrier();
      if (t + 2 < nt) {
        int sb = cur + 2; if (sb >= 3) sb -= 3;
        STAGE(sb, (t + 2) * 32);
      }

      bf16x8 av[4], bv[4];
      #pragma unroll
      for (int mi = 0; mi < 4; ++mi)
        av[mi] = *reinterpret_cast<const bf16x8*>(&As[cur][0] + (wm * 64 + mi * 16 + fr) * 32 + kg);
      #pragma unroll
      for (int nj = 0; nj < 4; ++nj) {
        int colOff = wn * 32 + (nj & 1) * 16 + (nj >> 1) * 64;   // remapped for RoPE pairing
        bv[nj] = *reinterpret_cast<const bf16x8*>(&Bs[cur][0] + (colOff + fr) * 32 + kg);
      }
      #pragma unroll
      for (int mi = 0; mi < 4; ++mi)
        #pragma unroll
        for (int nj = 0; nj < 4; ++nj)
          acc[mi][nj] = __builtin_amdgcn_mfma_f32_16x16x32_bf16(av[mi], bv[nj], acc[mi][nj], 0, 0, 0);

      cur = (cur == 2) ? 0 : cur + 1;
    }

    const float sc = 0.1275174485f;   // log2(e) / sqrt(128)
    const int nChunk = n0 >> 11;
    #pragma unroll
    for (int mi = 0; mi < 4; ++mi) {
      #pragma unroll
      for (int r = 0; r < 4; ++r) {
        int gr = m0 + wm * 64 + mi * 16 + g4 * 4 + r;
        if (gr >= SQ) continue;
        int st  = gr * 5 + nChunk;
        int tau = st % 1023;
        const float* ct  = cosT + tau * 64;
        const float* stb = sinT + tau * 64;
        #pragma unroll
        for (int njp = 0; njp < 2; ++njp) {
          int dd = wn * 32 + njp * 16 + fr;
          float c = ct[dd], s = stb[dd];
          float x0 = acc[mi][njp][r];
          float x1 = acc[mi][njp + 2][r];
          size_t base = (size_t)gr * 10240 + n0 + dd;
          qbb[base]      = f2bf_fast((x0 * c - x1 * s) * sc);
          qbb[base + 64] = f2bf_fast((x1 * c + x0 * s) * sc);
        }
      }
    }
  } else if (blockIdx.x < 896) {
    // ---------------- GEMM2 64x128 split-K x2 (kLen = 2048) ----
    const int u = blockIdx.x - 640;
    const int Kd = 4096, M = SQ, N = NKVC, kLen = 2048;
    const int n0 = (u & 7) * 128, m0 = ((u >> 3) & 15) * 64;
    const int kOff = (u >> 7) * kLen;
    float* C = kvp + (size_t)(u >> 7) * M * N;
    ushort_t* As64 = &As[0][0];
    ushort_t* Bs64 = &Bs[0][0];

    const int arow = tid >> 2, aslot = (tid & 3) * 8;
    const int l15 = lane & 15;

    f32x4 acc[2][4];
    #pragma unroll
    for (int i = 0; i < 2; ++i)
      #pragma unroll
      for (int j = 0; j < 4; ++j) acc[i][j] = (f32x4){0.f, 0.f, 0.f, 0.f};

    for (int k0 = kOff; k0 < kOff + kLen; k0 += 32) {
      {
        const ushort_t* ga = akv + (size_t)(m0 + arow) * Kd + k0 + aslot;
        __builtin_amdgcn_global_load_lds(
            (const __attribute__((address_space(1))) void*)ga,
            (__attribute__((address_space(3))) void*)(As64 + w * 512), 16, 0, 0);
      }
      #pragma unroll
      for (int c = 0; c < 2; ++c) {
        int uu = c * 256 + tid;
        const ushort_t* gb = wkvt + (size_t)(n0 + (uu >> 2)) * Kd + k0 + (uu & 3) * 8;
        __builtin_amdgcn_global_load_lds(
            (const __attribute__((address_space(1))) void*)gb,
            (__attribute__((address_space(3))) void*)(Bs64 + (c * 256 + w * 64) * 8), 16, 0, 0);
      }
      __syncthreads();

      bf16x8 av[2], bv[4];
      #pragma unroll
      for (int mi = 0; mi < 2; ++mi)
        av[mi] = *reinterpret_cast<const bf16x8*>(As64 + (wm * 32 + mi * 16 + fr) * 32 + kg);
      #pragma unroll
      for (int nj = 0; nj < 4; ++nj)
        bv[nj] = *reinterpret_cast<const bf16x8*>(Bs64 + (wn * 64 + nj * 16 + fr) * 32 + kg);
      #pragma unroll
      for (int mi = 0; mi < 2; ++mi)
        #pragma unroll
        for (int nj = 0; nj < 4; ++nj)
          acc[mi][nj] = __builtin_amdgcn_mfma_f32_16x16x32_bf16(av[mi], bv[nj], acc[mi][nj], 0, 0, 0);
      __syncthreads();
    }

    #pragma unroll
    for (int mi = 0; mi < 2; ++mi) {
      #pragma unroll
      for (int nj = 0; nj < 4; ++nj) {
        int rbase = m0 + wm * 32 + mi * 16 + g4 * 4;
        int col   = n0 + wn * 64 + nj * 16 + l15;
        #pragma unroll
        for (int r = 0; r < 4; ++r) {
          int gr = rbase + r;
          if (gr < M) C[(size_t)gr * N + col] = acc[mi][nj][r];
        }
      }
    }
  } else {
    // ---------------- tconv Wo (4096 blocks), reuses As as tile buffer ------
    int b2 = blockIdx.x - 896;
    float (&tsh)[32][33] = *reinterpret_cast<float(*)[32][33]>(&As[0][0]);
    tconv_body(Wo, wot, HIDC, HIDC, b2 % 64, b2 / 64, tid, tsh);
  }
}

// ============ k_kv: rope_k (blocks 0-1022) U vtrans (blocks 1023-1534) =======
// folds 2 GEMM2 split-K partials
__global__ __launch_bounds__(256)
void k_kv(const float* __restrict__ kvp, ushort_t* __restrict__ kb,
          ushort_t* __restrict__ vt, const float* __restrict__ cosT,
          const float* __restrict__ sinT)
{
  __shared__ float tile[32][33];
  const int tid = threadIdx.x;
  int b = blockIdx.x;
  if (b < 1023) {
    int idx = b * 256 + tid;
    if (idx >= SQ * 4 * 64) return;
    int d   = idx & 63;
    int kvh = (idx >> 6) & 3;
    int t   = idx >> 8;
    size_t src = (size_t)t * 1024 + kvh * 128 + d;
    float x0 = 0.f, x1 = 0.f;
    #pragma unroll
    for (int z = 0; z < 2; ++z) {
      x0 += kvp[(size_t)z * (SQ * 1024) + src];
      x1 += kvp[(size_t)z * (SQ * 1024) + src + 64];
    }
    float c = cosT[t * 64 + d], s = sinT[t * 64 + d];
    size_t dst = (size_t)t * 512 + kvh * 128 + d;
    kb[dst]      = f2bf(x0 * c - x1 * s);
    kb[dst + 64] = f2bf(x1 * c + x0 * s);
    return;
  }
  b -= 1023;
  {
    int v0 = (b & 15) * 32;
    int t0 = (b >> 4) * 32;
    int r = tid >> 5, c = tid & 31;
    #pragma unroll
    for (int p = 0; p < 4; ++p) {
      int t = t0 + p * 8 + r;
      float s = 0.f;
      if (t < SQ) {
        size_t src = (size_t)t * 1024 + 512 + v0 + c;
        #pragma unroll
        for (int z = 0; z < 2; ++z) s += kvp[(size_t)z * (SQ * 1024) + src];
      }
      tile[p * 8 + r][c] = s;
    }
    __syncthreads();
    #pragma unroll
    for (int p = 0; p < 4; ++p) {
      int v = v0 + p * 8 + r;
      vt[(size_t)v * 1024 + t0 + c] = f2bf(tile[c][p * 8 + r]);
    }
  }
}

// == bf16 MFMA GEMM, 128x128 tile, BK=32, 3-buffer + counted vmcnt (GEMM3) ====
__global__ __launch_bounds__(256)
void k_gemm3buf(const ushort_t* __restrict__ A, const ushort_t* __restrict__ Bt,
                float* __restrict__ C, int M, int N, int Kd)
{
  __shared__ __align__(16) ushort_t As[3][128 * 32];
  __shared__ __align__(16) ushort_t Bs[3][128 * 32];

  const int tid  = threadIdx.x;
  const int lane = tid & 63;
  const int w    = tid >> 6;
  const int wm   = w >> 1, wn = w & 1;
  const int fr   = lane & 15;
  const int kg   = (lane >> 4) * 8;
  const int m0   = blockIdx.y * 128, n0 = blockIdx.x * 128;

  const int lrow = lane >> 2;
  const int lk   = (lane & 3) * 8;

  f32x4 acc[4][4];
  #pragma unroll
  for (int i = 0; i < 4; ++i)
    #pragma unroll
    for (int j = 0; j < 4; ++j) acc[i][j] = (f32x4){0.f, 0.f, 0.f, 0.f};

  auto STAGE = [&](int b, int k0) {
    #pragma unroll
    for (int c = 0; c < 2; ++c) {
      int ch  = w + c * 4;
      int row = ch * 16 + lrow;
      const ushort_t* ga = A  + (size_t)(m0 + row) * Kd + k0 + lk;
      const ushort_t* gb = Bt + (size_t)(n0 + row) * Kd + k0 + lk;
      __builtin_amdgcn_global_load_lds(
          (const __attribute__((address_space(1))) void*)ga,
          (__attribute__((address_space(3))) void*)(&As[b][0] + ch * 512), 16, 0, 0);
      __builtin_amdgcn_global_load_lds(
          (const __attribute__((address_space(1))) void*)gb,
          (__attribute__((address_space(3))) void*)(&Bs[b][0] + ch * 512), 16, 0, 0);
    }
  };

  const int nt = Kd / 32;
  STAGE(0, 0);
  STAGE(1, 32);

  int cur = 0;
  for (int t = 0; t < nt; ++t) {
    if (t + 1 < nt) {
      asm volatile("s_waitcnt vmcnt(4)" ::: "memory");
    } else {
      asm volatile("s_waitcnt vmcnt(0)" ::: "memory");
    }
    __builtin_amdgcn_s_barrier();
    if (t + 2 < nt) {
      int sb = cur + 2; if (sb >= 3) sb -= 3;
      STAGE(sb, (t + 2) * 32);
    }

    bf16x8 av[4], bv[4];
    #pragma unroll
    for (int mi = 0; mi < 4; ++mi)
      av[mi] = *reinterpret_cast<const bf16x8*>(&As[cur][0] + (wm * 64 + mi * 16 + fr) * 32 + kg);
    #pragma unroll
    for (int nj = 0; nj < 4; ++nj)
      bv[nj] = *reinterpret_cast<const bf16x8*>(&Bs[cur][0] + (wn * 64 + nj * 16 + fr) * 32 + kg);
    #pragma unroll
    for (int mi = 0; mi < 4; ++mi)
      #pragma unroll
      for (int nj = 0; nj < 4; ++nj)
        acc[mi][nj] = __builtin_amdgcn_mfma_f32_16x16x32_bf16(av[mi], bv[nj], acc[mi][nj], 0, 0, 0);

    cur = (cur == 2) ? 0 : cur + 1;
  }

  #pragma unroll
  for (int mi = 0; mi < 4; ++mi) {
    #pragma unroll
    for (int nj = 0; nj < 4; ++nj) {
      int rbase = m0 + wm * 64 + mi * 16 + (lane >> 4) * 4;
      int col   = n0 + wn * 64 + nj * 16 + fr;
      #pragma unroll
      for (int r = 0; r < 4; ++r) {
        int gr = rbase + r;
        if (gr < M) C[(size_t)gr * N + col] = acc[mi][nj][r];
      }
    }
  }
}

// ======================= MFMA flash attention (swapped-QK, exp2 domain) ======
__global__ __launch_bounds__(256)
void k_attn_mfma(const ushort_t* __restrict__ qb, const ushort_t* __restrict__ kb,
                 const ushort_t* __restrict__ vt, ushort_t* __restrict__ oattb)
{
  __shared__ __align__(16) ushort_t Ks[64 * 128];
  __shared__ __align__(16) ushort_t Vs[128 * 64];
  __shared__ __align__(16) ushort_t Ps[4][16 * 64]; // per-wave P [16 q][64 kv], XOR-swz

  const int tid  = threadIdx.x;
  const int lane = tid & 63;
  const int w    = tid >> 6;
  const int l15  = lane & 15;
  const int g4   = lane >> 4;
  const int gh   = blockIdx.x;
  const int g = gh >> 4, h = gh & 15, kvh = (gh & 15) >> 2;
  const int qt = 15 - blockIdx.y;
  const int t0 = qt * 64;
  const int tq = t0 + w * 16 + l15;        // this lane's q row

  bf16x8 av[4];
  {
    const ushort_t* qrow = qb + (((size_t)(g * SQ + tq)) * 16 + h) * 128;
    #pragma unroll
    for (int kk = 0; kk < 4; ++kk)
      av[kk] = *reinterpret_cast<const bf16x8*>(qrow + kk * 32 + g4 * 8);
  }

  f32x4 acc[8];
  #pragma unroll
  for (int dt = 0; dt < 8; ++dt) acc[dt] = (f32x4){0.f, 0.f, 0.f, 0.f};
  float lsum = 0.f;
  float m = -1e30f;

  char* pwb = (char*)&Ps[w][0] + l15 * 128;   // this lane's P row (bytes)
  const int pswz = (l15 & 7) << 4;            // byte XOR within row

  for (int jt = 0; jt <= qt; ++jt) {
    int u0 = jt * 64;
    #pragma unroll
    for (int i = 0; i < 4; ++i) {
      int c = (w * 4 + i) * 64 + lane;
      int kv = c >> 4, sl = c & 15;
      const ushort_t* srck = kb + (size_t)(u0 + kv) * 512 + kvh * 128 + ((sl ^ (kv & 7)) << 3);
      __builtin_amdgcn_global_load_lds(
          (const __attribute__((address_space(1))) void*)srck,
          (__attribute__((address_space(3))) void*)(Ks + (w * 4 + i) * 512), 16, 0, 0);
      int d = c >> 3, sv = c & 7;
      const ushort_t* srcv = vt + (size_t)(kvh * 128 + d) * 1024 + u0 + ((sv ^ (d & 7)) << 3);
      __builtin_amdgcn_global_load_lds(
          (const __attribute__((address_space(1))) void*)srcv,
          (__attribute__((address_space(3))) void*)(Vs + (w * 4 + i) * 512), 16, 0, 0);
    }
    __syncthreads();

    // S^T = K Q^T  (S[ct][r]: row kv = ct*16 + g4*4 + r, col q = l15)
    f32x4 S[4];
    #pragma unroll
    for (int ct = 0; ct < 4; ++ct) S[ct] = (f32x4){0.f, 0.f, 0.f, 0.f};
    #pragma unroll
    for (int ct = 0; ct < 4; ++ct) {
      int kv = ct * 16 + l15;
      #pragma unroll
      for (int kk = 0; kk < 4; ++kk) {
        bf16x8 kvf = *reinterpret_cast<const bf16x8*>(
            Ks + kv * 128 + ((((kk << 2) | g4) ^ (kv & 7)) << 3));
        S[ct] = __builtin_amdgcn_mfma_f32_16x16x32_bf16(kvf, av[kk], S[ct], 0, 0, 0);
      }
    }
    // causal mask: u = u0 + ct*16 + g4*4 + r vs t = tq
    if (jt == qt) {
      #pragma unroll
      for (int ct = 0; ct < 4; ++ct) {
        int ub = u0 + ct * 16 + g4 * 4;
        #pragma unroll
        for (int r = 0; r < 4; ++r)
          if (ub + r > tq) S[ct][r] = -1e30f;
      }
    }
    // in-lane max tree + 2 shfl
    float a0 = fmaxf(fmaxf(S[0][0], S[0][1]), fmaxf(S[0][2], S[0][3]));
    float a1 = fmaxf(fmaxf(S[1][0], S[1][1]), fmaxf(S[1][2], S[1][3]));
    float a2 = fmaxf(fmaxf(S[2][0], S[2][1]), fmaxf(S[2][2], S[2][3]));
    float a3 = fmaxf(fmaxf(S[3][0], S[3][1]), fmaxf(S[3][2], S[3][3]));
    float tm = fmaxf(fmaxf(a0, a1), fmaxf(a2, a3));
    tm = fmaxf(tm, __shfl_xor(tm, 16));
    tm = fmaxf(tm, __shfl_xor(tm, 32));

    // defer-max (T13, log2 units: P bounded by 2^8)
    bool need = tm > m + 8.f;
    if (__any(need)) {
      float mn = fmaxf(m, tm);
      float corr = fexp2(m - mn);
      m = mn;
      lsum *= corr;
      #pragma unroll
      for (int dt = 0; dt < 8; ++dt) acc[dt] *= corr;
    }

    // exp + pack + b64 store + partial sum, per ct
    float ps = 0.f;
    #pragma unroll
    for (int ct = 0; ct < 4; ++ct) {
      float e0 = S[ct][0] - m;
      float e1 = S[ct][1] - m;
      float e2 = S[ct][2] - m;
      float e3 = S[ct][3] - m;
      fexp2x4(e0, e1, e2, e3);
      ps += (e0 + e1) + (e2 + e3);
      uint2 pv;
      pv.x = (uint32_t)f2bf_fast(e0) | ((uint32_t)f2bf_fast(e1) << 16);
      pv.y = (uint32_t)f2bf_fast(e2) | ((uint32_t)f2bf_fast(e3) << 16);
      *reinterpret_cast<uint2*>(pwb + ((ct * 32 + g4 * 8) ^ pswz)) = pv;
    }
    ps += __shfl_xor(ps, 16);
    ps += __shfl_xor(ps, 32);
    lsum += ps;

    // O^T += V^T P^T : acc[dt] rows d = dt*16 + g4*4 + r, col q = l15
    #pragma unroll
    for (int kk = 0; kk < 2; ++kk) {
      bf16x8 pa = *reinterpret_cast<const bf16x8*>(pwb + ((kk * 64 + g4 * 16) ^ pswz));
      #pragma unroll
      for (int dt = 0; dt < 8; ++dt) {
        int d = dt * 16 + l15;
        bf16x8 vv = *reinterpret_cast<const bf16x8*>(
            Vs + d * 64 + ((((kk << 2) | g4) ^ (d & 7)) << 3));
        acc[dt] = __builtin_amdgcn_mfma_f32_16x16x32_bf16(vv, pa, acc[dt], 0, 0, 0);
      }
    }
    __syncthreads();
  }

  // epilogue: lane writes O[tq][d = dt*16 + g4*4 + 0..3] as packed 8B
  if (tq < SQ) {
    float inv = 1.f / lsum;
    ushort_t* dst = oattb + ((size_t)(g * SQ + tq)) * 2048 + h * 128;
    #pragma unroll
    for (int dt = 0; dt < 8; ++dt) {
      uint2 ov;
      ov.x = (uint32_t)f2bf_fast(acc[dt][0] * inv) | ((uint32_t)f2bf_fast(acc[dt][1] * inv) << 16);
      ov.y = (uint32_t)f2bf_fast(acc[dt][2] * inv) | ((uint32_t)f2bf_fast(acc[dt][3] * inv) << 16);
      *reinterpret_cast<uint2*>(dst + dt * 16 + g4 * 4) = ov;
    }
  }
}

// ======================= launch =======================
extern "C" void kernel_launch(void* const* d_in, const int* in_sizes, int n_in,
                              void* d_out, int out_size, void* d_ws, size_t ws_size,
                              hipStream_t stream) {
  const float* hidden = (const float*)d_in[0];   // (1024, 2048)
  const float* prevh  = (const float*)d_in[1];   // (1023, 2048)
  const float* Wq     = (const float*)d_in[4];   // (2048, 10240)
  const float* Wkv    = (const float*)d_in[5];   // (4096, 1024)
  const float* Wo     = (const float*)d_in[6];   // (2048, 2048)
  float* out = (float*)d_out;                    // (5115, 2048)

  char* ws = (char*)d_ws;
  float*    kvp   = (float*)ws;                        ws += (size_t)2 * SQ * 1024 * 4;  // 2 split-K partials
  float*    cosT  = (float*)ws;                        ws += (size_t)65472 * 4;
  float*    sinT  = (float*)ws;                        ws += (size_t)65472 * 4;
  ushort_t* qbb   = (ushort_t*)ws;                     ws += (size_t)5120 * 2048 * 2;
  ushort_t* kb    = (ushort_t*)ws;                     ws += (size_t)1024 * 512 * 2;
  ushort_t* vtb   = (ushort_t*)ws;                     ws += (size_t)512 * 1024 * 2;
  ushort_t* hbf   = (ushort_t*)ws;                     ws += (size_t)1024 * 2048 * 2;
  ushort_t* akv   = (ushort_t*)ws;                     ws += (size_t)1024 * 4096 * 2;
  ushort_t* oattb = (ushort_t*)ws;                     ws += (size_t)5120 * 2048 * 2;
  ushort_t* wqt   = (ushort_t*)ws;                     ws += (size_t)10240 * 2048 * 2;
  ushort_t* wkvt  = (ushort_t*)ws;                     ws += (size_t)1024 * 4096 * 2;
  ushort_t* wot   = (ushort_t*)ws;                     ws += (size_t)2048 * 2048 * 2;

  // 1. preprocessing (tconv Wq,Wkv + prep + tables); Wo tconv moved to k_gemms
  k_pre<<<dim3(20480 + 4096 + 2046 + 256), dim3(256), 0, stream>>>(
      Wq, Wkv, hidden, prevh, wqt, wkvt, hbf, akv, cosT, sinT);

  // 2. GEMM1(+RoPE) U GEMM2 split-Kx2 U tconv(Wo)  (640 + 256 + 4096 blocks)
  k_gemms<<<dim3(640 + 256 + 4096), dim3(256), 0, stream>>>(
      hbf, wqt, qbb, cosT, sinT, akv, wkvt, kvp, Wo, wot);

  // 3. K rope + V transpose (fold 2 kv partials), one dispatch
  k_kv<<<dim3(1023 + 512), dim3(256), 0, stream>>>(kvp, kb, vtb, cosT, sinT);

  // 4. MFMA flash attention (swapped-QK) -> bf16 O
  k_attn_mfma<<<dim3(80, 16), dim3(256), 0, stream>>>(qbb, kb, vtb, oattb);

  // 5. out = O_att @ Wo
  k_gemm3buf<<<dim3(HIDC / 128, 40), dim3(256), 0, stream>>>(oattb, wot, out, 5115, HIDC, 2048);
}

// Round 15
// 244.406 us; speedup vs baseline: 1.0466x; 1.0021x over previous
//
#include <hip/hip_runtime.h>
#include <cstddef>
#include <cstdint>

#define SQ    1023
#define HIDC  2048
#define NQC   10240
#define NKVC  1024

typedef unsigned short ushort_t;
typedef __bf16 bf16x8 __attribute__((ext_vector_type(8)));
typedef float  f32x4  __attribute__((ext_vector_type(4)));

__device__ __forceinline__ ushort_t f2bf_fast(float x) {
  __bf16 b = (__bf16)x;
  return __builtin_bit_cast(ushort_t, b);
}

// raw v_exp_f32 (computes 2^x)
__device__ __forceinline__ float fexp2(float x) {
  float r;
  asm("v_exp_f32 %0, %1\n\ts_nop 0" : "=v"(r) : "v"(x));
  return r;
}

__device__ __forceinline__ void fexp2x4(float& a, float& b, float& c, float& d) {
  asm("v_exp_f32 %0, %0\n\t"
      "v_exp_f32 %1, %1\n\t"
      "v_exp_f32 %2, %2\n\t"
      "v_exp_f32 %3, %3\n\t"
      "s_nop 0"
      : "+v"(a), "+v"(b), "+v"(c), "+v"(d));
}

// ======================= shared tconv body =======================
__device__ __forceinline__ void tconv_body(const float* __restrict__ in,
                                           ushort_t* __restrict__ out,
                                           int K, int N, int bx, int by,
                                           int tid, float (&t)[32][33]) {
  int n0 = bx * 32, k0 = by * 32;
  int r = tid >> 5, c = tid & 31;
  #pragma unroll
  for (int p = 0; p < 4; ++p)
    t[p * 8 + r][c] = in[(size_t)(k0 + p * 8 + r) * N + n0 + c];
  __syncthreads();
  #pragma unroll
  for (int p = 0; p < 4; ++p)
    out[(size_t)(n0 + p * 8 + r) * K + k0 + c] = f2bf_fast(t[c][p * 8 + r]);
}

// ================= k_pre: tables U tconv(Wq,Wkv,Wo) U prep (one dispatch) ====
// block roles: [0,20480) tconv Wq | [20480,24576) tconv Wkv | [24576,28672)
// tconv Wo | [28672,30718) prep | [30718,30974) rope tables.
__global__ __launch_bounds__(256)
void k_pre(const float* __restrict__ Wq, const float* __restrict__ Wkv,
           const float* __restrict__ Wo, const float* __restrict__ hidden,
           const float* __restrict__ prevh,
           ushort_t* __restrict__ wqt, ushort_t* __restrict__ wkvt,
           ushort_t* __restrict__ wot, ushort_t* __restrict__ hbf,
           ushort_t* __restrict__ akv,
           float* __restrict__ cosT, float* __restrict__ sinT)
{
  __shared__ float tsh[32][33];
  const int tid = threadIdx.x;
  int b = blockIdx.x;
  if (b < 20480) { tconv_body(Wq, wqt, HIDC, NQC, b % 320, b / 320, tid, tsh); return; }
  b -= 20480;
  if (b < 4096)  { tconv_body(Wkv, wkvt, 4096, NKVC, b % 32, b / 32, tid, tsh); return; }
  b -= 4096;
  if (b < 4096)  { tconv_body(Wo, wot, HIDC, HIDC, b % 64, b / 64, tid, tsh); return; }
  b -= 4096;
  if (b < 2046) {
    int i = (b * 256 + tid) * 4;
    if (i >= SQ * 2048) return;
    int r = i >> 11, c = i & 2047;
    float4 h1 = *reinterpret_cast<const float4*>(hidden + (size_t)(r + 1) * 2048 + c);
    float4 h0 = *reinterpret_cast<const float4*>(hidden + (size_t)r * 2048 + c);
    float4 pv = *reinterpret_cast<const float4*>(prevh + (size_t)r * 2048 + c);
    uint2 a, bb, d;
    a.x  = (uint32_t)f2bf_fast(h1.x) | ((uint32_t)f2bf_fast(h1.y) << 16);
    a.y  = (uint32_t)f2bf_fast(h1.z) | ((uint32_t)f2bf_fast(h1.w) << 16);
    bb.x = (uint32_t)f2bf_fast(pv.x) | ((uint32_t)f2bf_fast(pv.y) << 16);
    bb.y = (uint32_t)f2bf_fast(pv.z) | ((uint32_t)f2bf_fast(pv.w) << 16);
    d.x  = (uint32_t)f2bf_fast(h0.x) | ((uint32_t)f2bf_fast(h0.y) << 16);
    d.y  = (uint32_t)f2bf_fast(h0.z) | ((uint32_t)f2bf_fast(h0.w) << 16);
    *reinterpret_cast<uint2*>(hbf + i) = a;
    *reinterpret_cast<uint2*>(akv + (size_t)r * 4096 + c) = bb;
    *reinterpret_cast<uint2*>(akv + (size_t)r * 4096 + 2048 + c) = d;
    return;
  }
  b -= 2046;
  {
    int idx = b * 256 + tid;
    if (idx >= SQ * 64) return;
    int t = idx >> 6, i = idx & 63;
    float inv = powf(10000.0f, -(float)i * (1.0f / 64.0f));
    float f = (float)t * inv;
    cosT[idx] = cosf(f);
    sinT[idx] = sinf(f);
  }
}

// ======== k_gemms: GEMM1+RoPE (blocks 0-639) U GEMM2 split-Kx2 (640-895) =====
__global__ __launch_bounds__(256)
void k_gemms(const ushort_t* __restrict__ hbf, const ushort_t* __restrict__ wqt,
             ushort_t* __restrict__ qbb, const float* __restrict__ cosT,
             const float* __restrict__ sinT,
             const ushort_t* __restrict__ akv, const ushort_t* __restrict__ wkvt,
             float* __restrict__ kvp)
{
  __shared__ __align__(16) ushort_t As[3][128 * 32];
  __shared__ __align__(16) ushort_t Bs[3][128 * 32];

  const int tid  = threadIdx.x;
  const int lane = tid & 63;
  const int w    = tid >> 6;
  const int wm   = w >> 1, wn = w & 1;
  const int fr   = lane & 15;
  const int kg   = (lane >> 4) * 8;
  const int g4   = lane >> 4;
  const int lrow = lane >> 2;
  const int lk   = (lane & 3) * 8;

  if (blockIdx.x < 640) {
    // ---------------- GEMM1 + fused RoPE (m97 3-buffer counted-vmcnt) -------
    const int Kd = 2048;
    const int m0 = (blockIdx.x / 80) * 128, n0 = (blockIdx.x % 80) * 128;
    const ushort_t* A  = hbf;
    const ushort_t* Bt = wqt;

    f32x4 acc[4][4];
    #pragma unroll
    for (int i = 0; i < 4; ++i)
      #pragma unroll
      for (int j = 0; j < 4; ++j) acc[i][j] = (f32x4){0.f, 0.f, 0.f, 0.f};

    auto STAGE = [&](int b, int k0) {
      #pragma unroll
      for (int c = 0; c < 2; ++c) {
        int ch  = w + c * 4;
        int row = ch * 16 + lrow;
        const ushort_t* ga = A  + (size_t)(m0 + row) * Kd + k0 + lk;
        const ushort_t* gb = Bt + (size_t)(n0 + row) * Kd + k0 + lk;
        __builtin_amdgcn_global_load_lds(
            (const __attribute__((address_space(1))) void*)ga,
            (__attribute__((address_space(3))) void*)(&As[b][0] + ch * 512), 16, 0, 0);
        __builtin_amdgcn_global_load_lds(
            (const __attribute__((address_space(1))) void*)gb,
            (__attribute__((address_space(3))) void*)(&Bs[b][0] + ch * 512), 16, 0, 0);
      }
    };

    const int nt = Kd / 32;
    STAGE(0, 0);
    STAGE(1, 32);

    int cur = 0;
    for (int t = 0; t < nt; ++t) {
      if (t + 1 < nt) {
        asm volatile("s_waitcnt vmcnt(4)" ::: "memory");
      } else {
        asm volatile("s_waitcnt vmcnt(0)" ::: "memory");
      }
      __builtin_amdgcn_s_barrier();
      if (t + 2 < nt) {
        int sb = cur + 2; if (sb >= 3) sb -= 3;
        STAGE(sb, (t + 2) * 32);
      }

      bf16x8 av[4], bv[4];
      #pragma unroll
      for (int mi = 0; mi < 4; ++mi)
        av[mi] = *reinterpret_cast<const bf16x8*>(&As[cur][0] + (wm * 64 + mi * 16 + fr) * 32 + kg);
      #pragma unroll
      for (int nj = 0; nj < 4; ++nj) {
        int colOff = wn * 32 + (nj & 1) * 16 + (nj >> 1) * 64;   // remapped for RoPE pairing
        bv[nj] = *reinterpret_cast<const bf16x8*>(&Bs[cur][0] + (colOff + fr) * 32 + kg);
      }
      #pragma unroll
      for (int mi = 0; mi < 4; ++mi)
        #pragma unroll
        for (int nj = 0; nj < 4; ++nj)
          acc[mi][nj] = __builtin_amdgcn_mfma_f32_16x16x32_bf16(av[mi], bv[nj], acc[mi][nj], 0, 0, 0);

      cur = (cur == 2) ? 0 : cur + 1;
    }

    const float sc = 0.1275174485f;   // log2(e) / sqrt(128)
    const int nChunk = n0 >> 11;
    #pragma unroll
    for (int mi = 0; mi < 4; ++mi) {
      #pragma unroll
      for (int r = 0; r < 4; ++r) {
        int gr = m0 + wm * 64 + mi * 16 + g4 * 4 + r;
        if (gr >= SQ) continue;
        int st  = gr * 5 + nChunk;
        int tau = st % 1023;
        const float* ct  = cosT + tau * 64;
        const float* stb = sinT + tau * 64;
        #pragma unroll
        for (int njp = 0; njp < 2; ++njp) {
          int dd = wn * 32 + njp * 16 + fr;
          float c = ct[dd], s = stb[dd];
          float x0 = acc[mi][njp][r];
          float x1 = acc[mi][njp + 2][r];
          size_t base = (size_t)gr * 10240 + n0 + dd;
          qbb[base]      = f2bf_fast((x0 * c - x1 * s) * sc);
          qbb[base + 64] = f2bf_fast((x1 * c + x0 * s) * sc);
        }
      }
    }
  } else {
    // ---------------- GEMM2 64x128 split-K x2 (kLen = 2048) ----
    const int u = blockIdx.x - 640;
    const int Kd = 4096, M = SQ, N = NKVC, kLen = 2048;
    const int n0 = (u & 7) * 128, m0 = ((u >> 3) & 15) * 64;
    const int kOff = (u >> 7) * kLen;
    float* C = kvp + (size_t)(u >> 7) * M * N;
    ushort_t* As64 = &As[0][0];
    ushort_t* Bs64 = &Bs[0][0];

    const int arow = tid >> 2, aslot = (tid & 3) * 8;
    const int l15 = lane & 15;

    f32x4 acc[2][4];
    #pragma unroll
    for (int i = 0; i < 2; ++i)
      #pragma unroll
      for (int j = 0; j < 4; ++j) acc[i][j] = (f32x4){0.f, 0.f, 0.f, 0.f};

    for (int k0 = kOff; k0 < kOff + kLen; k0 += 32) {
      {
        const ushort_t* ga = akv + (size_t)(m0 + arow) * Kd + k0 + aslot;
        __builtin_amdgcn_global_load_lds(
            (const __attribute__((address_space(1))) void*)ga,
            (__attribute__((address_space(3))) void*)(As64 + w * 512), 16, 0, 0);
      }
      #pragma unroll
      for (int c = 0; c < 2; ++c) {
        int uu = c * 256 + tid;
        const ushort_t* gb = wkvt + (size_t)(n0 + (uu >> 2)) * Kd + k0 + (uu & 3) * 8;
        __builtin_amdgcn_global_load_lds(
            (const __attribute__((address_space(1))) void*)gb,
            (__attribute__((address_space(3))) void*)(Bs64 + (c * 256 + w * 64) * 8), 16, 0, 0);
      }
      __syncthreads();

      bf16x8 av[2], bv[4];
      #pragma unroll
      for (int mi = 0; mi < 2; ++mi)
        av[mi] = *reinterpret_cast<const bf16x8*>(As64 + (wm * 32 + mi * 16 + fr) * 32 + kg);
      #pragma unroll
      for (int nj = 0; nj < 4; ++nj)
        bv[nj] = *reinterpret_cast<const bf16x8*>(Bs64 + (wn * 64 + nj * 16 + fr) * 32 + kg);
      #pragma unroll
      for (int mi = 0; mi < 2; ++mi)
        #pragma unroll
        for (int nj = 0; nj < 4; ++nj)
          acc[mi][nj] = __builtin_amdgcn_mfma_f32_16x16x32_bf16(av[mi], bv[nj], acc[mi][nj], 0, 0, 0);
      __syncthreads();
    }

    #pragma unroll
    for (int mi = 0; mi < 2; ++mi) {
      #pragma unroll
      for (int nj = 0; nj < 4; ++nj) {
        int rbase = m0 + wm * 32 + mi * 16 + g4 * 4;
        int col   = n0 + wn * 64 + nj * 16 + l15;
        #pragma unroll
        for (int r = 0; r < 4; ++r) {
          int gr = rbase + r;
          if (gr < M) C[(size_t)gr * N + col] = acc[mi][nj][r];
        }
      }
    }
  }
}

// ============ k_kv: rope_k (blocks 0-1022) U vtrans (blocks 1023-1534) =======
// folds 2 GEMM2 split-K partials
__global__ __launch_bounds__(256)
void k_kv(const float* __restrict__ kvp, ushort_t* __restrict__ kb,
          ushort_t* __restrict__ vt, const float* __restrict__ cosT,
          const float* __restrict__ sinT)
{
  __shared__ float tile[32][33];
  const int tid = threadIdx.x;
  int b = blockIdx.x;
  if (b < 1023) {
    int idx = b * 256 + tid;
    if (idx >= SQ * 4 * 64) return;
    int d   = idx & 63;
    int kvh = (idx >> 6) & 3;
    int t   = idx >> 8;
    size_t src = (size_t)t * 1024 + kvh * 128 + d;
    float x0 = 0.f, x1 = 0.f;
    #pragma unroll
    for (int z = 0; z < 2; ++z) {
      x0 += kvp[(size_t)z * (SQ * 1024) + src];
      x1 += kvp[(size_t)z * (SQ * 1024) + src + 64];
    }
    float c = cosT[t * 64 + d], s = sinT[t * 64 + d];
    size_t dst = (size_t)t * 512 + kvh * 128 + d;
    kb[dst]      = f2bf_fast(x0 * c - x1 * s);
    kb[dst + 64] = f2bf_fast(x1 * c + x0 * s);
    return;
  }
  b -= 1023;
  {
    int v0 = (b & 15) * 32;
    int t0 = (b >> 4) * 32;
    int r = tid >> 5, c = tid & 31;
    #pragma unroll
    for (int p = 0; p < 4; ++p) {
      int t = t0 + p * 8 + r;
      float s = 0.f;
      if (t < SQ) {
        size_t src = (size_t)t * 1024 + 512 + v0 + c;
        #pragma unroll
        for (int z = 0; z < 2; ++z) s += kvp[(size_t)z * (SQ * 1024) + src];
      }
      tile[p * 8 + r][c] = s;
    }
    __syncthreads();
    #pragma unroll
    for (int p = 0; p < 4; ++p) {
      int v = v0 + p * 8 + r;
      vt[(size_t)v * 1024 + t0 + c] = f2bf_fast(tile[c][p * 8 + r]);
    }
  }
}

// == bf16 MFMA GEMM, 128x128 tile, BK=32, 3-buffer + counted vmcnt (GEMM3) ====
__global__ __launch_bounds__(256)
void k_gemm3buf(const ushort_t* __restrict__ A, const ushort_t* __restrict__ Bt,
                float* __restrict__ C, int M, int N, int Kd)
{
  __shared__ __align__(16) ushort_t As[3][128 * 32];
  __shared__ __align__(16) ushort_t Bs[3][128 * 32];

  const int tid  = threadIdx.x;
  const int lane = tid & 63;
  const int w    = tid >> 6;
  const int wm   = w >> 1, wn = w & 1;
  const int fr   = lane & 15;
  const int kg   = (lane >> 4) * 8;
  const int m0   = blockIdx.y * 128, n0 = blockIdx.x * 128;

  const int lrow = lane >> 2;
  const int lk   = (lane & 3) * 8;

  f32x4 acc[4][4];
  #pragma unroll
  for (int i = 0; i < 4; ++i)
    #pragma unroll
    for (int j = 0; j < 4; ++j) acc[i][j] = (f32x4){0.f, 0.f, 0.f, 0.f};

  auto STAGE = [&](int b, int k0) {
    #pragma unroll
    for (int c = 0; c < 2; ++c) {
      int ch  = w + c * 4;
      int row = ch * 16 + lrow;
      const ushort_t* ga = A  + (size_t)(m0 + row) * Kd + k0 + lk;
      const ushort_t* gb = Bt + (size_t)(n0 + row) * Kd + k0 + lk;
      __builtin_amdgcn_global_load_lds(
          (const __attribute__((address_space(1))) void*)ga,
          (__attribute__((address_space(3))) void*)(&As[b][0] + ch * 512), 16, 0, 0);
      __builtin_amdgcn_global_load_lds(
          (const __attribute__((address_space(1))) void*)gb,
          (__attribute__((address_space(3))) void*)(&Bs[b][0] + ch * 512), 16, 0, 0);
    }
  };

  const int nt = Kd / 32;
  STAGE(0, 0);
  STAGE(1, 32);

  int cur = 0;
  for (int t = 0; t < nt; ++t) {
    if (t + 1 < nt) {
      asm volatile("s_waitcnt vmcnt(4)" ::: "memory");
    } else {
      asm volatile("s_waitcnt vmcnt(0)" ::: "memory");
    }
    __builtin_amdgcn_s_barrier();
    if (t + 2 < nt) {
      int sb = cur + 2; if (sb >= 3) sb -= 3;
      STAGE(sb, (t + 2) * 32);
    }

    bf16x8 av[4], bv[4];
    #pragma unroll
    for (int mi = 0; mi < 4; ++mi)
      av[mi] = *reinterpret_cast<const bf16x8*>(&As[cur][0] + (wm * 64 + mi * 16 + fr) * 32 + kg);
    #pragma unroll
    for (int nj = 0; nj < 4; ++nj)
      bv[nj] = *reinterpret_cast<const bf16x8*>(&Bs[cur][0] + (wn * 64 + nj * 16 + fr) * 32 + kg);
    #pragma unroll
    for (int mi = 0; mi < 4; ++mi)
      #pragma unroll
      for (int nj = 0; nj < 4; ++nj)
        acc[mi][nj] = __builtin_amdgcn_mfma_f32_16x16x32_bf16(av[mi], bv[nj], acc[mi][nj], 0, 0, 0);

    cur = (cur == 2) ? 0 : cur + 1;
  }

  #pragma unroll
  for (int mi = 0; mi < 4; ++mi) {
    #pragma unroll
    for (int nj = 0; nj < 4; ++nj) {
      int rbase = m0 + wm * 64 + mi * 16 + (lane >> 4) * 4;
      int col   = n0 + wn * 64 + nj * 16 + fr;
      #pragma unroll
      for (int r = 0; r < 4; ++r) {
        int gr = rbase + r;
        if (gr < M) C[(size_t)gr * N + col] = acc[mi][nj][r];
      }
    }
  }
}

// ======================= MFMA flash attention (swapped-QK, exp2 domain) ======
__global__ __launch_bounds__(256)
void k_attn_mfma(const ushort_t* __restrict__ qb, const ushort_t* __restrict__ kb,
                 const ushort_t* __restrict__ vt, ushort_t* __restrict__ oattb)
{
  __shared__ __align__(16) ushort_t Ks[64 * 128];
  __shared__ __align__(16) ushort_t Vs[128 * 64];
  __shared__ __align__(16) ushort_t Ps[4][16 * 64]; // per-wave P [16 q][64 kv], XOR-swz

  const int tid  = threadIdx.x;
  const int lane = tid & 63;
  const int w    = tid >> 6;
  const int l15  = lane & 15;
  const int g4   = lane >> 4;
  const int gh   = blockIdx.x;
  const int g = gh >> 4, h = gh & 15, kvh = (gh & 15) >> 2;
  const int qt = 15 - blockIdx.y;
  const int t0 = qt * 64;
  const int tq = t0 + w * 16 + l15;        // this lane's q row

  bf16x8 av[4];
  {
    const ushort_t* qrow = qb + (((size_t)(g * SQ + tq)) * 16 + h) * 128;
    #pragma unroll
    for (int kk = 0; kk < 4; ++kk)
      av[kk] = *reinterpret_cast<const bf16x8*>(qrow + kk * 32 + g4 * 8);
  }

  f32x4 acc[8];
  #pragma unroll
  for (int dt = 0; dt < 8; ++dt) acc[dt] = (f32x4){0.f, 0.f, 0.f, 0.f};
  float lsum = 0.f;
  float m = -1e30f;

  char* pwb = (char*)&Ps[w][0] + l15 * 128;   // this lane's P row (bytes)
  const int pswz = (l15 & 7) << 4;            // byte XOR within row

  for (int jt = 0; jt <= qt; ++jt) {
    int u0 = jt * 64;
    #pragma unroll
    for (int i = 0; i < 4; ++i) {
      int c = (w * 4 + i) * 64 + lane;
      int kv = c >> 4, sl = c & 15;
      const ushort_t* srck = kb + (size_t)(u0 + kv) * 512 + kvh * 128 + ((sl ^ (kv & 7)) << 3);
      __builtin_amdgcn_global_load_lds(
          (const __attribute__((address_space(1))) void*)srck,
          (__attribute__((address_space(3))) void*)(Ks + (w * 4 + i) * 512), 16, 0, 0);
      int d = c >> 3, sv = c & 7;
      const ushort_t* srcv = vt + (size_t)(kvh * 128 + d) * 1024 + u0 + ((sv ^ (d & 7)) << 3);
      __builtin_amdgcn_global_load_lds(
          (const __attribute__((address_space(1))) void*)srcv,
          (__attribute__((address_space(3))) void*)(Vs + (w * 4 + i) * 512), 16, 0, 0);
    }
    __syncthreads();

    // S^T = K Q^T  (S[ct][r]: row kv = ct*16 + g4*4 + r, col q = l15)
    f32x4 S[4];
    #pragma unroll
    for (int ct = 0; ct < 4; ++ct) S[ct] = (f32x4){0.f, 0.f, 0.f, 0.f};
    #pragma unroll
    for (int ct = 0; ct < 4; ++ct) {
      int kv = ct * 16 + l15;
      #pragma unroll
      for (int kk = 0; kk < 4; ++kk) {
        bf16x8 kvf = *reinterpret_cast<const bf16x8*>(
            Ks + kv * 128 + ((((kk << 2) | g4) ^ (kv & 7)) << 3));
        S[ct] = __builtin_amdgcn_mfma_f32_16x16x32_bf16(kvf, av[kk], S[ct], 0, 0, 0);
      }
    }
    // causal mask: u = u0 + ct*16 + g4*4 + r vs t = tq
    if (jt == qt) {
      #pragma unroll
      for (int ct = 0; ct < 4; ++ct) {
        int ub = u0 + ct * 16 + g4 * 4;
        #pragma unroll
        for (int r = 0; r < 4; ++r)
          if (ub + r > tq) S[ct][r] = -1e30f;
      }
    }
    // in-lane max tree + 2 shfl
    float a0 = fmaxf(fmaxf(S[0][0], S[0][1]), fmaxf(S[0][2], S[0][3]));
    float a1 = fmaxf(fmaxf(S[1][0], S[1][1]), fmaxf(S[1][2], S[1][3]));
    float a2 = fmaxf(fmaxf(S[2][0], S[2][1]), fmaxf(S[2][2], S[2][3]));
    float a3 = fmaxf(fmaxf(S[3][0], S[3][1]), fmaxf(S[3][2], S[3][3]));
    float tm = fmaxf(fmaxf(a0, a1), fmaxf(a2, a3));
    tm = fmaxf(tm, __shfl_xor(tm, 16));
    tm = fmaxf(tm, __shfl_xor(tm, 32));

    // defer-max (T13, log2 units: P bounded by 2^8)
    bool need = tm > m + 8.f;
    if (__any(need)) {
      float mn = fmaxf(m, tm);
      float corr = fexp2(m - mn);
      m = mn;
      lsum *= corr;
      #pragma unroll
      for (int dt = 0; dt < 8; ++dt) acc[dt] *= corr;
    }

    // exp + pack + b64 store + partial sum, per ct
    float ps = 0.f;
    #pragma unroll
    for (int ct = 0; ct < 4; ++ct) {
      float e0 = S[ct][0] - m;
      float e1 = S[ct][1] - m;
      float e2 = S[ct][2] - m;
      float e3 = S[ct][3] - m;
      fexp2x4(e0, e1, e2, e3);
      ps += (e0 + e1) + (e2 + e3);
      uint2 pv;
      pv.x = (uint32_t)f2bf_fast(e0) | ((uint32_t)f2bf_fast(e1) << 16);
      pv.y = (uint32_t)f2bf_fast(e2) | ((uint32_t)f2bf_fast(e3) << 16);
      *reinterpret_cast<uint2*>(pwb + ((ct * 32 + g4 * 8) ^ pswz)) = pv;
    }
    ps += __shfl_xor(ps, 16);
    ps += __shfl_xor(ps, 32);
    lsum += ps;

    // O^T += V^T P^T : acc[dt] rows d = dt*16 + g4*4 + r, col q = l15
    #pragma unroll
    for (int kk = 0; kk < 2; ++kk) {
      bf16x8 pa = *reinterpret_cast<const bf16x8*>(pwb + ((kk * 64 + g4 * 16) ^ pswz));
      #pragma unroll
      for (int dt = 0; dt < 8; ++dt) {
        int d = dt * 16 + l15;
        bf16x8 vv = *reinterpret_cast<const bf16x8*>(
            Vs + d * 64 + ((((kk << 2) | g4) ^ (d & 7)) << 3));
        acc[dt] = __builtin_amdgcn_mfma_f32_16x16x32_bf16(vv, pa, acc[dt], 0, 0, 0);
      }
    }
    __syncthreads();
  }

  // epilogue: lane writes O[tq][d = dt*16 + g4*4 + 0..3] as packed 8B
  if (tq < SQ) {
    float inv = 1.f / lsum;
    ushort_t* dst = oattb + ((size_t)(g * SQ + tq)) * 2048 + h * 128;
    #pragma unroll
    for (int dt = 0; dt < 8; ++dt) {
      uint2 ov;
      ov.x = (uint32_t)f2bf_fast(acc[dt][0] * inv) | ((uint32_t)f2bf_fast(acc[dt][1] * inv) << 16);
      ov.y = (uint32_t)f2bf_fast(acc[dt][2] * inv) | ((uint32_t)f2bf_fast(acc[dt][3] * inv) << 16);
      *reinterpret_cast<uint2*>(dst + dt * 16 + g4 * 4) = ov;
    }
  }
}

// ======================= launch =======================
extern "C" void kernel_launch(void* const* d_in, const int* in_sizes, int n_in,
                              void* d_out, int out_size, void* d_ws, size_t ws_size,
                              hipStream_t stream) {
  const float* hidden = (const float*)d_in[0];   // (1024, 2048)
  const float* prevh  = (const float*)d_in[1];   // (1023, 2048)
  const float* Wq     = (const float*)d_in[4];   // (2048, 10240)
  const float* Wkv    = (const float*)d_in[5];   // (4096, 1024)
  const float* Wo     = (const float*)d_in[6];   // (2048, 2048)
  float* out = (float*)d_out;                    // (5115, 2048)

  char* ws = (char*)d_ws;
  float*    kvp   = (float*)ws;                        ws += (size_t)2 * SQ * 1024 * 4;  // 2 split-K partials
  float*    cosT  = (float*)ws;                        ws += (size_t)65472 * 4;
  float*    sinT  = (float*)ws;                        ws += (size_t)65472 * 4;
  ushort_t* qbb   = (ushort_t*)ws;                     ws += (size_t)5120 * 2048 * 2;
  ushort_t* kb    = (ushort_t*)ws;                     ws += (size_t)1024 * 512 * 2;
  ushort_t* vtb   = (ushort_t*)ws;                     ws += (size_t)512 * 1024 * 2;
  ushort_t* hbf   = (ushort_t*)ws;                     ws += (size_t)1024 * 2048 * 2;
  ushort_t* akv   = (ushort_t*)ws;                     ws += (size_t)1024 * 4096 * 2;
  ushort_t* oattb = (ushort_t*)ws;                     ws += (size_t)5120 * 2048 * 2;
  ushort_t* wqt   = (ushort_t*)ws;                     ws += (size_t)10240 * 2048 * 2;
  ushort_t* wkvt  = (ushort_t*)ws;                     ws += (size_t)1024 * 4096 * 2;
  ushort_t* wot   = (ushort_t*)ws;                     ws += (size_t)2048 * 2048 * 2;

  // 1. all preprocessing in one dispatch (tconv x3 + prep + tables)
  k_pre<<<dim3(20480 + 4096 + 4096 + 2046 + 256), dim3(256), 0, stream>>>(
      Wq, Wkv, Wo, hidden, prevh, wqt, wkvt, wot, hbf, akv, cosT, sinT);

  // 2. GEMM1(+RoPE) and GEMM2 split-Kx2 co-scheduled (640 + 256 blocks)
  k_gemms<<<dim3(640 + 256), dim3(256), 0, stream>>>(
      hbf, wqt, qbb, cosT, sinT, akv, wkvt, kvp);

  // 3. K rope + V transpose (fold 2 kv partials), one dispatch
  k_kv<<<dim3(1023 + 512), dim3(256), 0, stream>>>(kvp, kb, vtb, cosT, sinT);

  // 4. MFMA flash attention (swapped-QK) -> bf16 O
  k_attn_mfma<<<dim3(80, 16), dim3(256), 0, stream>>>(qbb, kb, vtb, oattb);

  // 5. out = O_att @ Wo
  k_gemm3buf<<<dim3(HIDC / 128, 40), dim3(256), 0, stream>>>(oattb, wot, out, 5115, HIDC, 2048);
}